// Round 1
// 402.417 us; speedup vs baseline: 1.0338x; 1.0338x over previous
//
#include <hip/hip_runtime.h>
#include <cstdint>
#include <cstddef>

// ---------------------------------------------------------------------------
// EnzymeCompoundCrossAttention — R4: weight-folded scores.
//
// Algebra (R1/R2 verified, extended):
//   score = x_q (Wq Wk^T) x_k^T / S + (x_k . (Wk bq)) / S   (+iw bias; bk and
//   q-constant terms cancel in softmax).
//   es/ep share (enz_Wq, enz_Wk) -> one M_big. se/pe re-associated as
//   P = enz @ M^T so ALL big GEMMs collapse into Y = enz @ W3 with
//   W3t = [M_big^T | M_se-gen | M_pe-gen | u_s | u_p | 0pad]  [896 x 1280].
//   Score GEMMs contract over d_cpd=256 (was d_out=512).
//   out_quarter = (1/Lq) * (wsum @ X_kv) @ Wv + bv  (unchanged tail).
// Launches: prep -> fold -> y_gemm -> score -> colsum2 -> wx -> out (7).
// ---------------------------------------------------------------------------

#define SCALE_INV 0.044194173824159216f  // 1/sqrt(512)

typedef short bf16x8 __attribute__((ext_vector_type(8)));
typedef float f32x4  __attribute__((ext_vector_type(4)));

__device__ __forceinline__ ushort f2bf(float f) {
  union { float f; unsigned u; } c; c.f = f;
  unsigned u = c.u + 0x7fffu + ((c.u >> 16) & 1u);
  return (ushort)(u >> 16);
}
__device__ __forceinline__ float bf2f(ushort h) {
  return __uint_as_float(((unsigned)h) << 16);
}
__device__ __forceinline__ void gload16(const ushort* g, ushort* l) {
  __builtin_amdgcn_global_load_lds(
      (const __attribute__((address_space(1))) void*)g,
      (__attribute__((address_space(3))) void*)l, 16, 0, 0);
}

// ---------------------------------------------------------------------------
// Kernel 1: prep — segmented flat grid. Grid 13483.
//   [0,10240)      cvt enz f32->bf16 (20,971,520 elems, 8/thread)
//   [10240,10752)  cvt sub (1,048,576)
//   [10752,11264)  cvt prod
//   [11264,12416)  cvt 6 weight mats to bf16 (natural layout, no transpose)
//   [12416,12592)  u vectors: u_s,u_p -> W3t rows 768/769 (bf16);
//                  u_e * SCALE_INV -> f32[256]
//   [12592,13168)  zero 147456 floats (wsum/l/wx region)
//   [13168,13483)  zero W3t rows 770..895 (80640 uints)
// ---------------------------------------------------------------------------
__device__ __forceinline__ void cvt8(const float* __restrict__ in,
                                     ushort* __restrict__ out, int blk, int n) {
  int i = (blk * 256 + (int)threadIdx.x) * 8;
  if (i >= n) return;
  float4 a = *(const float4*)(in + i);
  float4 b = *(const float4*)(in + i + 4);
  ushort o[8] = { f2bf(a.x), f2bf(a.y), f2bf(a.z), f2bf(a.w),
                  f2bf(b.x), f2bf(b.y), f2bf(b.z), f2bf(b.w) };
  *(uint4*)(out + i) = *(uint4*)o;
}

__global__ __launch_bounds__(256) void prep_fused(
    const float* __restrict__ enz, const float* __restrict__ sub,
    const float* __restrict__ prod,
    ushort* __restrict__ enz_b, ushort* __restrict__ sub_b, ushort* __restrict__ prod_b,
    const float* __restrict__ enz_Wq, const float* __restrict__ enz_Wk,
    const float* __restrict__ sub_Wq, const float* __restrict__ sub_Wk,
    const float* __restrict__ prod_Wq, const float* __restrict__ prod_Wk,
    ushort* __restrict__ eWq_b, ushort* __restrict__ eWk_b,
    ushort* __restrict__ sWq_b, ushort* __restrict__ sWk_b,
    ushort* __restrict__ pWq_b, ushort* __restrict__ pWk_b,
    const float* __restrict__ enz_bq, const float* __restrict__ sub_bq,
    const float* __restrict__ prod_bq,
    ushort* __restrict__ W3t, float* __restrict__ u_e_s,
    float* __restrict__ zero_base)
{
  const int f = blockIdx.x, t = threadIdx.x;
  if (f < 10240) { cvt8(enz, enz_b, f, 20971520); return; }
  if (f < 10752) { cvt8(sub, sub_b, f - 10240, 1048576); return; }
  if (f < 11264) { cvt8(prod, prod_b, f - 10752, 1048576); return; }
  if (f < 12416) {
    const int l = f - 11264;
    if (l < 320)       cvt8(enz_Wq,  eWq_b, l,        655360);
    else if (l < 640)  cvt8(sub_Wk,  sWk_b, l - 320,  655360);
    else if (l < 960)  cvt8(prod_Wk, pWk_b, l - 640,  655360);
    else if (l < 1024) cvt8(enz_Wk,  eWk_b, l - 960,  131072);
    else if (l < 1088) cvt8(sub_Wq,  sWq_b, l - 1024, 131072);
    else               cvt8(prod_Wq, pWq_b, l - 1088, 131072);
    return;
  }
  if (f < 12592) {
    // u[d] = dot(Wk[d,:512], bq). 16 rows/block, 16 threads/row.
    const int g = f - 12416;
    const float* W; const float* bv; int d0, kind;
    if (g < 80)       { W = sub_Wk;  bv = sub_bq;  d0 = g * 16;         kind = 0; }
    else if (g < 160) { W = prod_Wk; bv = prod_bq; d0 = (g - 80) * 16;  kind = 1; }
    else              { W = enz_Wk;  bv = enz_bq;  d0 = (g - 160) * 16; kind = 2; }
    const int r = t >> 4, i = t & 15, d = d0 + r;
    const float* row = W + (size_t)d * 512;
    float s = 0.f;
#pragma unroll
    for (int j = 0; j < 32; j++) s += row[i + j * 16] * bv[i + j * 16];
    s += __shfl_xor(s, 1); s += __shfl_xor(s, 2);
    s += __shfl_xor(s, 4); s += __shfl_xor(s, 8);
    if (i == 0) {
      if (kind < 2) W3t[(size_t)(768 + kind) * 1280 + d] = f2bf(s);
      else          u_e_s[d] = s * SCALE_INV;
    }
    return;
  }
  if (f < 13168) { zero_base[(f - 12592) * 256 + t] = 0.f; return; }
  {
    const int idx = (f - 13168) * 256 + t;  // < 80640
    ((unsigned*)(W3t + (size_t)770 * 1280))[idx] = 0u;
  }
}

// ---------------------------------------------------------------------------
// MFMA tile core: 128x128, 256 threads, BK=32, bf16 in / f32 acc.
// A-frag lane: A[m=lane&15][ (lane>>4)*8 .. +7 ];  C/D: col=lane&15,
// row=(lane>>4)*4+reg  (guide §3, m89-verified).
// ---------------------------------------------------------------------------
__device__ __forceinline__ void mfma_tile(
    const ushort* __restrict__ A, int lda,
    const ushort* __restrict__ Bt, int ldb, int K,
    int bm, int bn, ushort* AsBase, ushort* BsBase, f32x4 (&acc)[4][4])
{
  const int t = threadIdx.x, wave = t >> 6, lane = t & 63;
  const int srow = wave * 16 + (lane >> 2);
  const int sseg = (lane & 3) * 8;
  const ushort* Ag0 = A + (size_t)(bm + srow) * lda + sseg;
  const ushort* Ag1 = Ag0 + (size_t)64 * lda;
  const ushort* Bg0 = Bt + (size_t)(bn + srow) * ldb + sseg;
  const ushort* Bg1 = Bg0 + (size_t)64 * ldb;
  ushort* AsP0 = AsBase + srow * 32 + sseg;
  ushort* AsP1 = AsP0 + 64 * 32;
  ushort* BsP0 = BsBase + srow * 32 + sseg;
  ushort* BsP1 = BsP0 + 64 * 32;
  const int wm = (wave >> 1) * 64, wn = (wave & 1) * 64;
  const int fl = lane & 15, fq = lane >> 4;
  const bf16x8* ArP = (const bf16x8*)(AsBase + (wm + fl) * 32 + fq * 8);
  const bf16x8* BrP = (const bf16x8*)(BsBase + (wn + fl) * 32 + fq * 8);
  for (int k0 = 0; k0 < K; k0 += 32) {
    __syncthreads();
    gload16(Ag0 + k0, AsP0);
    gload16(Ag1 + k0, AsP1);
    gload16(Bg0 + k0, BsP0);
    gload16(Bg1 + k0, BsP1);
    __syncthreads();
    bf16x8 af[4], bfr[4];
#pragma unroll
    for (int i = 0; i < 4; i++) af[i] = ArP[i * 64];
#pragma unroll
    for (int j = 0; j < 4; j++) bfr[j] = BrP[j * 64];
#pragma unroll
    for (int i = 0; i < 4; i++)
#pragma unroll
      for (int j = 0; j < 4; j++)
        acc[i][j] = __builtin_amdgcn_mfma_f32_16x16x32_bf16(af[i], bfr[j], acc[i][j], 0, 0, 0);
  }
}

// ---------------------------------------------------------------------------
// Kernel 2: fold — W3t rows 0..767 via 3 MFMA GEMMs, K=512, all operands in
// natural layout. Grid 60: seg = f/20 in {es/ep, se, pe}; 2 mtiles x 10 ntiles.
//   seg0: W3t[c,d]     = sum_n enz_Wk[c,n]  enz_Wq[d,n]
//   seg1: W3t[256+c,d] = sum_n sub_Wq[c,n]  sub_Wk[d,n]
//   seg2: W3t[512+c,d] = sum_n prod_Wq[c,n] prod_Wk[d,n]
// ---------------------------------------------------------------------------
__global__ __launch_bounds__(256) void fold_w3(
    const ushort* __restrict__ eWq_b, const ushort* __restrict__ eWk_b,
    const ushort* __restrict__ sWq_b, const ushort* __restrict__ sWk_b,
    const ushort* __restrict__ pWq_b, const ushort* __restrict__ pWk_b,
    ushort* __restrict__ W3t)
{
  __shared__ __align__(16) ushort As[128 * 32];
  __shared__ __align__(16) ushort Bs[128 * 32];
  const int f = blockIdx.x, seg = f / 20, l = f % 20;
  const int bm = (l / 10) * 128, bn = (l % 10) * 128;
  const ushort* A  = (seg == 0) ? eWk_b : (seg == 1) ? sWq_b : pWq_b;
  const ushort* Bt = (seg == 0) ? eWq_b : (seg == 1) ? sWk_b : pWk_b;
  f32x4 acc[4][4] = {};
  mfma_tile(A, 512, Bt, 512, 512, bm, bn, As, Bs, acc);
  const int lane = threadIdx.x & 63, wave = threadIdx.x >> 6;
  const int wm = (wave >> 1) * 64, wn = (wave & 1) * 64;
  const int fl = lane & 15, fq = lane >> 4;
#pragma unroll
  for (int i = 0; i < 4; i++)
#pragma unroll
    for (int j = 0; j < 4; j++) {
      const int col = bn + wn + j * 16 + fl;
#pragma unroll
      for (int r = 0; r < 4; r++) {
        const int row = seg * 256 + bm + wm + i * 16 + fq * 4 + r;
        W3t[(size_t)row * 1280 + col] = f2bf(acc[i][j][r]);
      }
    }
}

// ---------------------------------------------------------------------------
// Kernel 3: Y = enz @ W3  (M=16384, N=896, K=1280). Grid 896. XCD swizzle:
// xcd = f&7 owns mtiles [xcd*16, xcd*16+16), N-fastest within.
// Y cols: [0,256)=es/ep operand, [256,512)=P_se, [512,768)=P_pe,
// 768/769 = t_se/t_pe bias terms, [770,896) = 0.
// ---------------------------------------------------------------------------
__global__ __launch_bounds__(256) void y_gemm(
    const ushort* __restrict__ enz_b, const ushort* __restrict__ W3t,
    ushort* __restrict__ Y)
{
  __shared__ __align__(16) ushort As[128 * 32];
  __shared__ __align__(16) ushort Bs[128 * 32];
  const int f = blockIdx.x;
  const int xcd = f & 7, slot = f >> 3;
  const int bm = (xcd * 16 + slot / 7) * 128, bn = (slot % 7) * 128;
  f32x4 acc[4][4] = {};
  mfma_tile(enz_b, 1280, W3t, 1280, 1280, bm, bn, As, Bs, acc);
  const int lane = threadIdx.x & 63, wave = threadIdx.x >> 6;
  const int wm = (wave >> 1) * 64, wn = (wave & 1) * 64;
  const int fl = lane & 15, fq = lane >> 4;
#pragma unroll
  for (int i = 0; i < 4; i++)
#pragma unroll
    for (int j = 0; j < 4; j++) {
      const int col = bn + wn + j * 16 + fl;
#pragma unroll
      for (int r = 0; r < 4; r++) {
        const int row = bm + wm + i * 16 + fq * 4 + r;
        Y[(size_t)row * 896 + col] = f2bf(acc[i][j][r]);
      }
    }
}

// ---------------------------------------------------------------------------
// Kernel 4: all 4 score GEMMs + softmax plumbing. Grid 512. K=256 now.
//   [0,256)    es/ep: A = Y[:,0:256] rows, Bt = sub/prod (N=128 = full Lk) ->
//              exp + row-sum + normalized col-sum in-block, atomicAdd wsum.
//              bias t[k] = dot(x_k, u_e_scaled) computed in-block; es adds iw.
//   [256,512)  se/pe: A = sub/prod (M=128 = full Lq), Bt = Y P-cols, N-tile
//              128 of 512 -> exp -> Sc + partial row sums. t from Y col 768/769.
// ---------------------------------------------------------------------------
__global__ __launch_bounds__(256) void score_fused(
    const ushort* __restrict__ Y, const ushort* __restrict__ sub_b,
    const ushort* __restrict__ prod_b, const float* __restrict__ iw,
    const float* __restrict__ u_e_s,
    float* __restrict__ Sc_se, float* __restrict__ Sc_pe,
    float* __restrict__ l_se, float* __restrict__ l_pe,
    float* __restrict__ wsum_es, float* __restrict__ wsum_ep)
{
  __shared__ __align__(16) ushort As[128 * 32];
  __shared__ __align__(16) ushort Bs[128 * 32];
  __shared__ float red[2][128];
  __shared__ float red2[2][128];
  __shared__ float tsh[128];
  const int f = blockIdx.x, t = threadIdx.x;
  const int lane = t & 63, wave = t >> 6;
  const int wm = (wave >> 1) * 64, wn = (wave & 1) * 64;
  const int fl = lane & 15, fq = lane >> 4;
  f32x4 acc[4][4] = {};

  if (f < 256) {
    // ---- es / ep ----
    const int path = f >> 7, l = f & 127, b = l & 31, mt = l >> 5;
    const int bm = mt * 128;
    const ushort* X = (path ? prod_b : sub_b) + (size_t)b * 32768;
    {   // tsh[k] = SCALE_INV * dot(X[k,:], u_e)  (u_e_s pre-scaled)
      const int col = t >> 1, half = t & 1;
      const ushort* xr = X + col * 256 + half * 128;
      const float* uu = u_e_s + half * 128;
      float s = 0.f;
      for (int c = 0; c < 128; c++) s += bf2f(xr[c]) * uu[c];
      s += __shfl_xor(s, 1);
      if (!half) tsh[col] = s;
    }   // mfma_tile's first __syncthreads orders tsh for all readers
    mfma_tile(Y + (size_t)b * 512 * 896, 896, X, 256, 256, bm, 0, As, Bs, acc);
    const size_t ib = (size_t)b * 65536;
    float rsum[4][4];
#pragma unroll
    for (int i = 0; i < 4; i++)
#pragma unroll
      for (int r = 0; r < 4; r++) rsum[i][r] = 0.f;
#pragma unroll
    for (int i = 0; i < 4; i++)
#pragma unroll
      for (int j = 0; j < 4; j++)
#pragma unroll
        for (int r = 0; r < 4; r++) {
          const int row = wm + i * 16 + fq * 4 + r;   // local q
          const int col = wn + j * 16 + fl;           // k (global, bn=0)
          float s = acc[i][j][r] * SCALE_INV + tsh[col];
          if (path == 0) s += iw[ib + (size_t)col * 512 + (bm + row)];
          const float e = __expf(s);
          acc[i][j][r] = e;
          rsum[i][r] += e;
        }
#pragma unroll
    for (int m = 1; m <= 8; m <<= 1)
#pragma unroll
      for (int i = 0; i < 4; i++)
#pragma unroll
        for (int r = 0; r < 4; r++)
          rsum[i][r] += __shfl_xor(rsum[i][r], m);
    if (fl == 0)
#pragma unroll
      for (int i = 0; i < 4; i++)
#pragma unroll
        for (int r = 0; r < 4; r++)
          red[wave & 1][wm + i * 16 + fq * 4 + r] = rsum[i][r];
    __syncthreads();
    float csum[4] = { 0.f, 0.f, 0.f, 0.f };
#pragma unroll
    for (int i = 0; i < 4; i++)
#pragma unroll
      for (int r = 0; r < 4; r++) {
        const int row = wm + i * 16 + fq * 4 + r;
        const float invr = 1.f / (red[0][row] + red[1][row]);
#pragma unroll
        for (int j = 0; j < 4; j++) csum[j] += acc[i][j][r] * invr;
      }
#pragma unroll
    for (int m = 16; m <= 32; m <<= 1)
#pragma unroll
      for (int j = 0; j < 4; j++) csum[j] += __shfl_xor(csum[j], m);
    if (fq == 0)
#pragma unroll
      for (int j = 0; j < 4; j++) red2[wave >> 1][wn + j * 16 + fl] = csum[j];
    __syncthreads();
    float* ws = (path ? wsum_ep : wsum_es) + b * 128;
    if (t < 128) atomicAdd(&ws[t], red2[0][t] + red2[1][t]);
  } else {
    // ---- se / pe ----
    const int g = f - 256, path = g >> 7, l = g & 127, b = l & 31, nt = l >> 5;
    const int bn = nt * 128;
    const ushort* A  = (path ? prod_b : sub_b) + (size_t)b * 32768;
    const ushort* Bt = Y + (size_t)b * 512 * 896 + 256 + path * 256;
    mfma_tile(A, 256, Bt, 896, 256, 0, bn, As, Bs, acc);
    const size_t ib = (size_t)b * 65536;
    float* Sc = (path ? Sc_pe : Sc_se) + ib;
    float tv[4];
#pragma unroll
    for (int j = 0; j < 4; j++) {
      const int col = wn + j * 16 + fl;
      tv[j] = bf2f(Y[(size_t)(b * 512 + bn + col) * 896 + 768 + path]) * SCALE_INV;
    }
    float rsum[4][4];
#pragma unroll
    for (int i = 0; i < 4; i++)
#pragma unroll
      for (int r = 0; r < 4; r++) rsum[i][r] = 0.f;
#pragma unroll
    for (int i = 0; i < 4; i++)
#pragma unroll
      for (int j = 0; j < 4; j++)
#pragma unroll
        for (int r = 0; r < 4; r++) {
          const int row = wm + i * 16 + fq * 4 + r;   // q (global, bm=0)
          const int col = wn + j * 16 + fl;           // local k
          float s = acc[i][j][r] * SCALE_INV + tv[j];
          if (path == 0) s += iw[ib + (size_t)row * 512 + (bn + col)];
          const float e = __expf(s);
          Sc[(size_t)row * 512 + bn + col] = e;
          rsum[i][r] += e;
        }
#pragma unroll
    for (int m = 1; m <= 8; m <<= 1)
#pragma unroll
      for (int i = 0; i < 4; i++)
#pragma unroll
        for (int r = 0; r < 4; r++)
          rsum[i][r] += __shfl_xor(rsum[i][r], m);
    if (fl == 0)
#pragma unroll
      for (int i = 0; i < 4; i++)
#pragma unroll
        for (int r = 0; r < 4; r++)
          red[wave & 1][wm + i * 16 + fq * 4 + r] = rsum[i][r];
    __syncthreads();
    float* lr = (path ? l_pe : l_se) + b * 128;
    if (t < 128) atomicAdd(&lr[t], red[0][t] + red[1][t]);
  }
}

// ---------------------------------------------------------------------------
// Kernel 5: finish se/pe colsum: wsum[b,k] += sum_q Sc[b,q,k] / l[b,q].
// ---------------------------------------------------------------------------
__global__ __launch_bounds__(256) void colsum2(
    const float* __restrict__ Sc_se, const float* __restrict__ Sc_pe,
    const float* __restrict__ l_se, const float* __restrict__ l_pe,
    float* __restrict__ wsum_se, float* __restrict__ wsum_pe)
{
  __shared__ float inv[32];
  const int f = blockIdx.x, t = threadIdx.x;
  const int path = f >> 7, l = f & 127, b = l & 31, qc = l >> 5;
  const float* Sc = (path ? Sc_pe : Sc_se) + (size_t)b * 65536 + (size_t)(qc * 32) * 512;
  const float* lv = (path ? l_pe : l_se) + b * 128 + qc * 32;
  float* ws = (path ? wsum_pe : wsum_se) + b * 512;
  if (t < 32) inv[t] = 1.f / lv[t];
  __syncthreads();
  float a0 = 0.f, a1 = 0.f;
  for (int q = 0; q < 32; q++) {
    const float iq = inv[q];
    a0 += Sc[(size_t)q * 512 + t] * iq;
    a1 += Sc[(size_t)q * 512 + 256 + t] * iq;
  }
  atomicAdd(&ws[t], a0);
  atomicAdd(&ws[t + 256], a1);
}

// ---------------------------------------------------------------------------
// Kernel 6: wx = wsum @ X_kv (bf16 X). Grid 384.
// ---------------------------------------------------------------------------
__global__ __launch_bounds__(256) void wx_fused(
    const float* __restrict__ wsum_se, const float* __restrict__ wsum_pe,
    const float* __restrict__ wsum_es, const float* __restrict__ wsum_ep,
    const ushort* __restrict__ enz_b, const ushort* __restrict__ sub_b,
    const ushort* __restrict__ prod_b,
    float* __restrict__ wx_se, float* __restrict__ wx_pe,
    float* __restrict__ wx_es, float* __restrict__ wx_ep)
{
  __shared__ float wse[256], wpe[256];
  const int f = blockIdx.x, t = threadIdx.x;
  if (f < 320) {
    const int ch = f % 5, tmp = f / 5, b = tmp & 31, kh = tmp >> 5;
    wse[t] = wsum_se[b * 512 + kh * 256 + t];
    wpe[t] = wsum_pe[b * 512 + kh * 256 + t];
    __syncthreads();
    const int c = ch * 256 + t;
    const ushort* X = enz_b + (size_t)b * 512 * 1280 + (size_t)(kh * 256) * 1280 + c;
    float a_se = 0.f, a_pe = 0.f;
    for (int k = 0; k < 256; k++) {
      const float x = bf2f(X[(size_t)k * 1280]);
      a_se += wse[k] * x;
      a_pe += wpe[k] * x;
    }
    atomicAdd(&wx_se[b * 1280 + c], a_se);
    atomicAdd(&wx_pe[b * 1280 + c], a_pe);
  } else if (f < 352) {
    const int b = f - 320;
    const ushort* X = sub_b + (size_t)b * 128 * 256 + t;
    float a = 0.f;
    for (int k = 0; k < 128; k++) a += wsum_es[b * 128 + k] * bf2f(X[(size_t)k * 256]);
    wx_es[b * 256 + t] = a;
  } else {
    const int b = f - 352;
    const ushort* X = prod_b + (size_t)b * 128 * 256 + t;
    float a = 0.f;
    for (int k = 0; k < 128; k++) a += wsum_ep[b * 128 + k] * bf2f(X[(size_t)k * 256]);
    wx_ep[b * 256 + t] = a;
  }
}

// ---------------------------------------------------------------------------
// Kernel 7: out[b, qoff+n] = invLq * (wx[b,:] @ Wv)[n] + bv[n]. Grid (32,4).
// ---------------------------------------------------------------------------
__global__ __launch_bounds__(256) void out_fused(
    const float* __restrict__ wx_es, const float* __restrict__ wx_se,
    const float* __restrict__ wx_ep, const float* __restrict__ wx_pe,
    const float* __restrict__ enz_Wv, const float* __restrict__ enz_bv,
    const float* __restrict__ sub_Wv, const float* __restrict__ sub_bv,
    const float* __restrict__ prod_Wv, const float* __restrict__ prod_bv,
    float* __restrict__ out)
{
  __shared__ float sw[1280];
  const int b = blockIdx.x, p = blockIdx.y;
  const float *wx, *Wv, *bv; int Cdim, qoff; float inv;
  switch (p) {
    case 0:  wx = wx_es; Wv = enz_Wv;  bv = enz_bv;  Cdim = 256;  inv = 1.f / 512.f; qoff = 0;    break;
    case 1:  wx = wx_se; Wv = sub_Wv;  bv = sub_bv;  Cdim = 1280; inv = 1.f / 128.f; qoff = 512;  break;
    case 2:  wx = wx_ep; Wv = enz_Wv;  bv = enz_bv;  Cdim = 256;  inv = 1.f / 512.f; qoff = 1024; break;
    default: wx = wx_pe; Wv = prod_Wv; bv = prod_bv; Cdim = 1280; inv = 1.f / 128.f; qoff = 1536; break;
  }
  for (int i = threadIdx.x; i < Cdim; i += 256) sw[i] = wx[(size_t)b * Cdim + i];
  __syncthreads();
  const int n = threadIdx.x;
  float a0 = 0.f, a1 = 0.f;
  for (int c = 0; c < Cdim; c++) {
    const float w = sw[c];
    a0 += w * Wv[(size_t)c * 512 + n];
    a1 += w * Wv[(size_t)c * 512 + n + 256];
  }
  out[(size_t)b * 2048 + qoff + n]       = a0 * inv + bv[n];
  out[(size_t)b * 2048 + qoff + n + 256] = a1 * inv + bv[n + 256];
}

// ---------------------------------------------------------------------------
extern "C" void kernel_launch(void* const* d_in, const int* in_sizes, int n_in,
                              void* d_out, int out_size, void* d_ws, size_t ws_size,
                              hipStream_t stream)
{
  (void)in_sizes; (void)n_in; (void)out_size; (void)ws_size;
  const float* enz     = (const float*)d_in[0];   // [32,512,1280]
  const float* sub     = (const float*)d_in[1];   // [32,128,256]
  const float* prod    = (const float*)d_in[2];   // [32,128,256]
  const float* iw      = (const float*)d_in[6];   // [32,128,512]
  const float* enz_Wq  = (const float*)d_in[7];
  const float* enz_bq  = (const float*)d_in[8];
  const float* enz_Wk  = (const float*)d_in[9];
  const float* enz_Wv  = (const float*)d_in[11];
  const float* enz_bv  = (const float*)d_in[12];
  const float* sub_Wq  = (const float*)d_in[13];
  const float* sub_bq  = (const float*)d_in[14];
  const float* sub_Wk  = (const float*)d_in[15];
  const float* sub_Wv  = (const float*)d_in[17];
  const float* sub_bv  = (const float*)d_in[18];
  const float* prod_Wq = (const float*)d_in[19];
  const float* prod_bq = (const float*)d_in[20];
  const float* prod_Wk = (const float*)d_in[21];
  const float* prod_Wv = (const float*)d_in[23];
  const float* prod_bv = (const float*)d_in[24];
  float* out = (float*)d_out;

  char* wsb = (char*)d_ws;
  size_t off = 0;
  auto alloc = [&](size_t bytes) {
    void* p = wsb + off;
    off += (bytes + 255) & ~(size_t)255;
    return p;
  };
  ushort* enz_b   = (ushort*)alloc((size_t)32 * 512 * 1280 * 2);
  ushort* sub_b   = (ushort*)alloc((size_t)32 * 128 * 256 * 2);
  ushort* prod_b  = (ushort*)alloc((size_t)32 * 128 * 256 * 2);
  ushort* eWq_b   = (ushort*)alloc((size_t)1280 * 512 * 2);
  ushort* sWk_b   = (ushort*)alloc((size_t)1280 * 512 * 2);
  ushort* pWk_b   = (ushort*)alloc((size_t)1280 * 512 * 2);
  ushort* eWk_b   = (ushort*)alloc((size_t)256 * 512 * 2);
  ushort* sWq_b   = (ushort*)alloc((size_t)256 * 512 * 2);
  ushort* pWq_b   = (ushort*)alloc((size_t)256 * 512 * 2);
  ushort* W3t     = (ushort*)alloc((size_t)896 * 1280 * 2);
  ushort* Y       = (ushort*)alloc((size_t)16384 * 896 * 2);
  float*  u_e_s   = (float*)alloc(256 * 4);
  float*  Sc_se   = (float*)alloc((size_t)32 * 128 * 512 * 4);
  float*  Sc_pe   = (float*)alloc((size_t)32 * 128 * 512 * 4);
  // zero region (contiguous; sizes are 256B multiples): 147456 floats total
  float* wsum_es = (float*)alloc(4096 * 4);
  float* wsum_ep = (float*)alloc(4096 * 4);
  float* wsum_se = (float*)alloc(16384 * 4);
  float* wsum_pe = (float*)alloc(16384 * 4);
  float* l_se    = (float*)alloc(4096 * 4);
  float* l_pe    = (float*)alloc(4096 * 4);
  float* wx_se   = (float*)alloc(40960 * 4);
  float* wx_pe   = (float*)alloc(40960 * 4);
  float* wx_es   = (float*)alloc(8192 * 4);
  float* wx_ep   = (float*)alloc(8192 * 4);

  const dim3 blk(256);

  prep_fused<<<13483, blk, 0, stream>>>(
      enz, sub, prod, enz_b, sub_b, prod_b,
      enz_Wq, enz_Wk, sub_Wq, sub_Wk, prod_Wq, prod_Wk,
      eWq_b, eWk_b, sWq_b, sWk_b, pWq_b, pWk_b,
      enz_bq, sub_bq, prod_bq,
      W3t, u_e_s, wsum_es);

  fold_w3<<<60, blk, 0, stream>>>(eWq_b, eWk_b, sWq_b, sWk_b, pWq_b, pWk_b, W3t);

  y_gemm<<<896, blk, 0, stream>>>(enz_b, W3t, Y);

  score_fused<<<512, blk, 0, stream>>>(
      Y, sub_b, prod_b, iw, u_e_s, Sc_se, Sc_pe, l_se, l_pe, wsum_es, wsum_ep);

  colsum2<<<256, blk, 0, stream>>>(Sc_se, Sc_pe, l_se, l_pe, wsum_se, wsum_pe);

  wx_fused<<<384, blk, 0, stream>>>(
      wsum_se, wsum_pe, wsum_es, wsum_ep, enz_b, sub_b, prod_b,
      wx_se, wx_pe, wx_es, wx_ep);

  out_fused<<<dim3(32, 4), blk, 0, stream>>>(
      wx_es, wx_se, wx_ep, wx_pe,
      enz_Wv, enz_bv, sub_Wv, sub_bv, prod_Wv, prod_bv, out);
}

// Round 2
// 333.343 us; speedup vs baseline: 1.2480x; 1.2072x over previous
//
#include <hip/hip_runtime.h>
#include <cstdint>
#include <cstddef>

// ---------------------------------------------------------------------------
// EnzymeCompoundCrossAttention — R5: parallel epilogue GEMV.
//
// Algebra (R1/R2/R4 verified):
//   score = x_q (Wq Wk^T) x_k^T / S + (x_k . (Wk bq)) / S   (+iw bias; bk and
//   q-constant terms cancel in softmax).
//   es/ep share (enz_Wq, enz_Wk) -> one M_big. se/pe re-associated as
//   P = enz @ M^T so ALL big GEMMs collapse into Y = enz @ W3 with
//   W3t = [M_big^T | M_se-gen | M_pe-gen | u_s | u_p | 0pad]  [896 x 1280].
//   Score GEMMs contract over d_cpd=256.
//   out_quarter = (1/Lq) * (wsum @ X_kv) @ Wv + bv.
// R5: out GEMV split over c-chunks (was 3.3% occupancy, 93 us, latency-bound);
//   bias pre-init in prep; atomicAdd accumulate.
// Launches: prep -> fold -> y_gemm -> score -> colsum2 -> wx -> out (7).
// ---------------------------------------------------------------------------

#define SCALE_INV 0.044194173824159216f  // 1/sqrt(512)

typedef short bf16x8 __attribute__((ext_vector_type(8)));
typedef float f32x4  __attribute__((ext_vector_type(4)));

__device__ __forceinline__ ushort f2bf(float f) {
  union { float f; unsigned u; } c; c.f = f;
  unsigned u = c.u + 0x7fffu + ((c.u >> 16) & 1u);
  return (ushort)(u >> 16);
}
__device__ __forceinline__ float bf2f(ushort h) {
  return __uint_as_float(((unsigned)h) << 16);
}
__device__ __forceinline__ void gload16(const ushort* g, ushort* l) {
  __builtin_amdgcn_global_load_lds(
      (const __attribute__((address_space(1))) void*)g,
      (__attribute__((address_space(3))) void*)l, 16, 0, 0);
}

// ---------------------------------------------------------------------------
// Kernel 1: prep — segmented flat grid. Grid 13739.
//   [0,10240)      cvt enz f32->bf16 (20,971,520 elems, 8/thread)
//   [10240,10752)  cvt sub (1,048,576)
//   [10752,11264)  cvt prod
//   [11264,12416)  cvt 6 weight mats to bf16 (natural layout, no transpose)
//   [12416,12592)  u vectors: u_s,u_p -> W3t rows 768/769 (bf16);
//                  u_e * SCALE_INV -> f32[256]
//   [12592,13168)  zero 147456 floats (wsum/l/wx region)
//   [13168,13483)  zero W3t rows 770..895 (80640 uints)
//   [13483,13739)  out init = bias (65536 floats; out_gemv atomicAdds later)
// ---------------------------------------------------------------------------
__device__ __forceinline__ void cvt8(const float* __restrict__ in,
                                     ushort* __restrict__ out, int blk, int n) {
  int i = (blk * 256 + (int)threadIdx.x) * 8;
  if (i >= n) return;
  float4 a = *(const float4*)(in + i);
  float4 b = *(const float4*)(in + i + 4);
  ushort o[8] = { f2bf(a.x), f2bf(a.y), f2bf(a.z), f2bf(a.w),
                  f2bf(b.x), f2bf(b.y), f2bf(b.z), f2bf(b.w) };
  *(uint4*)(out + i) = *(uint4*)o;
}

__global__ __launch_bounds__(256) void prep_fused(
    const float* __restrict__ enz, const float* __restrict__ sub,
    const float* __restrict__ prod,
    ushort* __restrict__ enz_b, ushort* __restrict__ sub_b, ushort* __restrict__ prod_b,
    const float* __restrict__ enz_Wq, const float* __restrict__ enz_Wk,
    const float* __restrict__ sub_Wq, const float* __restrict__ sub_Wk,
    const float* __restrict__ prod_Wq, const float* __restrict__ prod_Wk,
    ushort* __restrict__ eWq_b, ushort* __restrict__ eWk_b,
    ushort* __restrict__ sWq_b, ushort* __restrict__ sWk_b,
    ushort* __restrict__ pWq_b, ushort* __restrict__ pWk_b,
    const float* __restrict__ enz_bq, const float* __restrict__ sub_bq,
    const float* __restrict__ prod_bq,
    const float* __restrict__ enz_bv, const float* __restrict__ sub_bv,
    const float* __restrict__ prod_bv,
    ushort* __restrict__ W3t, float* __restrict__ u_e_s,
    float* __restrict__ zero_base, float* __restrict__ out)
{
  const int f = blockIdx.x, t = threadIdx.x;
  if (f < 10240) { cvt8(enz, enz_b, f, 20971520); return; }
  if (f < 10752) { cvt8(sub, sub_b, f - 10240, 1048576); return; }
  if (f < 11264) { cvt8(prod, prod_b, f - 10752, 1048576); return; }
  if (f < 12416) {
    const int l = f - 11264;
    if (l < 320)       cvt8(enz_Wq,  eWq_b, l,        655360);
    else if (l < 640)  cvt8(sub_Wk,  sWk_b, l - 320,  655360);
    else if (l < 960)  cvt8(prod_Wk, pWk_b, l - 640,  655360);
    else if (l < 1024) cvt8(enz_Wk,  eWk_b, l - 960,  131072);
    else if (l < 1088) cvt8(sub_Wq,  sWq_b, l - 1024, 131072);
    else               cvt8(prod_Wq, pWq_b, l - 1088, 131072);
    return;
  }
  if (f < 12592) {
    // u[d] = dot(Wk[d,:512], bq). 16 rows/block, 16 threads/row.
    const int g = f - 12416;
    const float* W; const float* bv; int d0, kind;
    if (g < 80)       { W = sub_Wk;  bv = sub_bq;  d0 = g * 16;         kind = 0; }
    else if (g < 160) { W = prod_Wk; bv = prod_bq; d0 = (g - 80) * 16;  kind = 1; }
    else              { W = enz_Wk;  bv = enz_bq;  d0 = (g - 160) * 16; kind = 2; }
    const int r = t >> 4, i = t & 15, d = d0 + r;
    const float* row = W + (size_t)d * 512;
    float s = 0.f;
#pragma unroll
    for (int j = 0; j < 32; j++) s += row[i + j * 16] * bv[i + j * 16];
    s += __shfl_xor(s, 1); s += __shfl_xor(s, 2);
    s += __shfl_xor(s, 4); s += __shfl_xor(s, 8);
    if (i == 0) {
      if (kind < 2) W3t[(size_t)(768 + kind) * 1280 + d] = f2bf(s);
      else          u_e_s[d] = s * SCALE_INV;
    }
    return;
  }
  if (f < 13168) { zero_base[(f - 12592) * 256 + t] = 0.f; return; }
  if (f < 13483) {
    const int idx = (f - 13168) * 256 + t;  // < 80640
    ((unsigned*)(W3t + (size_t)770 * 1280))[idx] = 0u;
    return;
  }
  {
    const int idx = (f - 13483) * 256 + t;  // < 65536 = 32*2048
    const int col = idx & 2047;
    const int q = col >> 9, n = col & 511;
    const float* bvp = (q == 1) ? sub_bv : (q == 3) ? prod_bv : enz_bv;
    out[idx] = bvp[n];
  }
}

// ---------------------------------------------------------------------------
// MFMA tile core: 128x128, 256 threads, BK=32, bf16 in / f32 acc.
// A-frag lane: A[m=lane&15][ (lane>>4)*8 .. +7 ];  C/D: col=lane&15,
// row=(lane>>4)*4+reg  (guide §3, m89-verified).
// ---------------------------------------------------------------------------
__device__ __forceinline__ void mfma_tile(
    const ushort* __restrict__ A, int lda,
    const ushort* __restrict__ Bt, int ldb, int K,
    int bm, int bn, ushort* AsBase, ushort* BsBase, f32x4 (&acc)[4][4])
{
  const int t = threadIdx.x, wave = t >> 6, lane = t & 63;
  const int srow = wave * 16 + (lane >> 2);
  const int sseg = (lane & 3) * 8;
  const ushort* Ag0 = A + (size_t)(bm + srow) * lda + sseg;
  const ushort* Ag1 = Ag0 + (size_t)64 * lda;
  const ushort* Bg0 = Bt + (size_t)(bn + srow) * ldb + sseg;
  const ushort* Bg1 = Bg0 + (size_t)64 * ldb;
  ushort* AsP0 = AsBase + srow * 32 + sseg;
  ushort* AsP1 = AsP0 + 64 * 32;
  ushort* BsP0 = BsBase + srow * 32 + sseg;
  ushort* BsP1 = BsP0 + 64 * 32;
  const int wm = (wave >> 1) * 64, wn = (wave & 1) * 64;
  const int fl = lane & 15, fq = lane >> 4;
  const bf16x8* ArP = (const bf16x8*)(AsBase + (wm + fl) * 32 + fq * 8);
  const bf16x8* BrP = (const bf16x8*)(BsBase + (wn + fl) * 32 + fq * 8);
  for (int k0 = 0; k0 < K; k0 += 32) {
    __syncthreads();
    gload16(Ag0 + k0, AsP0);
    gload16(Ag1 + k0, AsP1);
    gload16(Bg0 + k0, BsP0);
    gload16(Bg1 + k0, BsP1);
    __syncthreads();
    bf16x8 af[4], bfr[4];
#pragma unroll
    for (int i = 0; i < 4; i++) af[i] = ArP[i * 64];
#pragma unroll
    for (int j = 0; j < 4; j++) bfr[j] = BrP[j * 64];
#pragma unroll
    for (int i = 0; i < 4; i++)
#pragma unroll
      for (int j = 0; j < 4; j++)
        acc[i][j] = __builtin_amdgcn_mfma_f32_16x16x32_bf16(af[i], bfr[j], acc[i][j], 0, 0, 0);
  }
}

// ---------------------------------------------------------------------------
// Kernel 2: fold — W3t rows 0..767 via 3 MFMA GEMMs, K=512, all operands in
// natural layout. Grid 60: seg = f/20 in {es/ep, se, pe}; 2 mtiles x 10 ntiles.
// ---------------------------------------------------------------------------
__global__ __launch_bounds__(256) void fold_w3(
    const ushort* __restrict__ eWq_b, const ushort* __restrict__ eWk_b,
    const ushort* __restrict__ sWq_b, const ushort* __restrict__ sWk_b,
    const ushort* __restrict__ pWq_b, const ushort* __restrict__ pWk_b,
    ushort* __restrict__ W3t)
{
  __shared__ __align__(16) ushort As[128 * 32];
  __shared__ __align__(16) ushort Bs[128 * 32];
  const int f = blockIdx.x, seg = f / 20, l = f % 20;
  const int bm = (l / 10) * 128, bn = (l % 10) * 128;
  const ushort* A  = (seg == 0) ? eWk_b : (seg == 1) ? sWq_b : pWq_b;
  const ushort* Bt = (seg == 0) ? eWq_b : (seg == 1) ? sWk_b : pWk_b;
  f32x4 acc[4][4] = {};
  mfma_tile(A, 512, Bt, 512, 512, bm, bn, As, Bs, acc);
  const int lane = threadIdx.x & 63, wave = threadIdx.x >> 6;
  const int wm = (wave >> 1) * 64, wn = (wave & 1) * 64;
  const int fl = lane & 15, fq = lane >> 4;
#pragma unroll
  for (int i = 0; i < 4; i++)
#pragma unroll
    for (int j = 0; j < 4; j++) {
      const int col = bn + wn + j * 16 + fl;
#pragma unroll
      for (int r = 0; r < 4; r++) {
        const int row = seg * 256 + bm + wm + i * 16 + fq * 4 + r;
        W3t[(size_t)row * 1280 + col] = f2bf(acc[i][j][r]);
      }
    }
}

// ---------------------------------------------------------------------------
// Kernel 3: Y = enz @ W3  (M=16384, N=896, K=1280). Grid 896. XCD swizzle:
// xcd = f&7 owns mtiles [xcd*16, xcd*16+16), N-fastest within.
// Y cols: [0,256)=es/ep operand, [256,512)=P_se, [512,768)=P_pe,
// 768/769 = t_se/t_pe bias terms, [770,896) = 0.
// ---------------------------------------------------------------------------
__global__ __launch_bounds__(256) void y_gemm(
    const ushort* __restrict__ enz_b, const ushort* __restrict__ W3t,
    ushort* __restrict__ Y)
{
  __shared__ __align__(16) ushort As[128 * 32];
  __shared__ __align__(16) ushort Bs[128 * 32];
  const int f = blockIdx.x;
  const int xcd = f & 7, slot = f >> 3;
  const int bm = (xcd * 16 + slot / 7) * 128, bn = (slot % 7) * 128;
  f32x4 acc[4][4] = {};
  mfma_tile(enz_b, 1280, W3t, 1280, 1280, bm, bn, As, Bs, acc);
  const int lane = threadIdx.x & 63, wave = threadIdx.x >> 6;
  const int wm = (wave >> 1) * 64, wn = (wave & 1) * 64;
  const int fl = lane & 15, fq = lane >> 4;
#pragma unroll
  for (int i = 0; i < 4; i++)
#pragma unroll
    for (int j = 0; j < 4; j++) {
      const int col = bn + wn + j * 16 + fl;
#pragma unroll
      for (int r = 0; r < 4; r++) {
        const int row = bm + wm + i * 16 + fq * 4 + r;
        Y[(size_t)row * 896 + col] = f2bf(acc[i][j][r]);
      }
    }
}

// ---------------------------------------------------------------------------
// Kernel 4: all 4 score GEMMs + softmax plumbing. Grid 512. K=256.
//   [0,256)    es/ep: A = Y[:,0:256] rows, Bt = sub/prod (N=128 = full Lk) ->
//              exp + row-sum + normalized col-sum in-block, atomicAdd wsum.
//              bias t[k] = dot(x_k, u_e_scaled) computed in-block; es adds iw.
//   [256,512)  se/pe: A = sub/prod (M=128 = full Lq), Bt = Y P-cols, N-tile
//              128 of 512 -> exp -> Sc + partial row sums. t from Y col 768/769.
// ---------------------------------------------------------------------------
__global__ __launch_bounds__(256) void score_fused(
    const ushort* __restrict__ Y, const ushort* __restrict__ sub_b,
    const ushort* __restrict__ prod_b, const float* __restrict__ iw,
    const float* __restrict__ u_e_s,
    float* __restrict__ Sc_se, float* __restrict__ Sc_pe,
    float* __restrict__ l_se, float* __restrict__ l_pe,
    float* __restrict__ wsum_es, float* __restrict__ wsum_ep)
{
  __shared__ __align__(16) ushort As[128 * 32];
  __shared__ __align__(16) ushort Bs[128 * 32];
  __shared__ float red[2][128];
  __shared__ float red2[2][128];
  __shared__ float tsh[128];
  const int f = blockIdx.x, t = threadIdx.x;
  const int lane = t & 63, wave = t >> 6;
  const int wm = (wave >> 1) * 64, wn = (wave & 1) * 64;
  const int fl = lane & 15, fq = lane >> 4;
  f32x4 acc[4][4] = {};

  if (f < 256) {
    // ---- es / ep ----
    const int path = f >> 7, l = f & 127, b = l & 31, mt = l >> 5;
    const int bm = mt * 128;
    const ushort* X = (path ? prod_b : sub_b) + (size_t)b * 32768;
    {   // tsh[k] = SCALE_INV * dot(X[k,:], u_e)  (u_e_s pre-scaled)
      const int col = t >> 1, half = t & 1;
      const ushort* xr = X + col * 256 + half * 128;
      const float* uu = u_e_s + half * 128;
      float s = 0.f;
      for (int c = 0; c < 128; c++) s += bf2f(xr[c]) * uu[c];
      s += __shfl_xor(s, 1);
      if (!half) tsh[col] = s;
    }   // mfma_tile's first __syncthreads orders tsh for all readers
    mfma_tile(Y + (size_t)b * 512 * 896, 896, X, 256, 256, bm, 0, As, Bs, acc);
    const size_t ib = (size_t)b * 65536;
    float rsum[4][4];
#pragma unroll
    for (int i = 0; i < 4; i++)
#pragma unroll
      for (int r = 0; r < 4; r++) rsum[i][r] = 0.f;
#pragma unroll
    for (int i = 0; i < 4; i++)
#pragma unroll
      for (int j = 0; j < 4; j++)
#pragma unroll
        for (int r = 0; r < 4; r++) {
          const int row = wm + i * 16 + fq * 4 + r;   // local q
          const int col = wn + j * 16 + fl;           // k (global, bn=0)
          float s = acc[i][j][r] * SCALE_INV + tsh[col];
          if (path == 0) s += iw[ib + (size_t)col * 512 + (bm + row)];
          const float e = __expf(s);
          acc[i][j][r] = e;
          rsum[i][r] += e;
        }
#pragma unroll
    for (int m = 1; m <= 8; m <<= 1)
#pragma unroll
      for (int i = 0; i < 4; i++)
#pragma unroll
        for (int r = 0; r < 4; r++)
          rsum[i][r] += __shfl_xor(rsum[i][r], m);
    if (fl == 0)
#pragma unroll
      for (int i = 0; i < 4; i++)
#pragma unroll
        for (int r = 0; r < 4; r++)
          red[wave & 1][wm + i * 16 + fq * 4 + r] = rsum[i][r];
    __syncthreads();
    float csum[4] = { 0.f, 0.f, 0.f, 0.f };
#pragma unroll
    for (int i = 0; i < 4; i++)
#pragma unroll
      for (int r = 0; r < 4; r++) {
        const int row = wm + i * 16 + fq * 4 + r;
        const float invr = 1.f / (red[0][row] + red[1][row]);
#pragma unroll
        for (int j = 0; j < 4; j++) csum[j] += acc[i][j][r] * invr;
      }
#pragma unroll
    for (int m = 16; m <= 32; m <<= 1)
#pragma unroll
      for (int j = 0; j < 4; j++) csum[j] += __shfl_xor(csum[j], m);
    if (fq == 0)
#pragma unroll
      for (int j = 0; j < 4; j++) red2[wave >> 1][wn + j * 16 + fl] = csum[j];
    __syncthreads();
    float* ws = (path ? wsum_ep : wsum_es) + b * 128;
    if (t < 128) atomicAdd(&ws[t], red2[0][t] + red2[1][t]);
  } else {
    // ---- se / pe ----
    const int g = f - 256, path = g >> 7, l = g & 127, b = l & 31, nt = l >> 5;
    const int bn = nt * 128;
    const ushort* A  = (path ? prod_b : sub_b) + (size_t)b * 32768;
    const ushort* Bt = Y + (size_t)b * 512 * 896 + 256 + path * 256;
    mfma_tile(A, 256, Bt, 896, 256, 0, bn, As, Bs, acc);
    const size_t ib = (size_t)b * 65536;
    float* Sc = (path ? Sc_pe : Sc_se) + ib;
    float tv[4];
#pragma unroll
    for (int j = 0; j < 4; j++) {
      const int col = wn + j * 16 + fl;
      tv[j] = bf2f(Y[(size_t)(b * 512 + bn + col) * 896 + 768 + path]) * SCALE_INV;
    }
    float rsum[4][4];
#pragma unroll
    for (int i = 0; i < 4; i++)
#pragma unroll
      for (int r = 0; r < 4; r++) rsum[i][r] = 0.f;
#pragma unroll
    for (int i = 0; i < 4; i++)
#pragma unroll
      for (int j = 0; j < 4; j++)
#pragma unroll
        for (int r = 0; r < 4; r++) {
          const int row = wm + i * 16 + fq * 4 + r;   // q (global, bm=0)
          const int col = wn + j * 16 + fl;           // local k
          float s = acc[i][j][r] * SCALE_INV + tv[j];
          if (path == 0) s += iw[ib + (size_t)row * 512 + (bn + col)];
          const float e = __expf(s);
          Sc[(size_t)row * 512 + bn + col] = e;
          rsum[i][r] += e;
        }
#pragma unroll
    for (int m = 1; m <= 8; m <<= 1)
#pragma unroll
      for (int i = 0; i < 4; i++)
#pragma unroll
        for (int r = 0; r < 4; r++)
          rsum[i][r] += __shfl_xor(rsum[i][r], m);
    if (fl == 0)
#pragma unroll
      for (int i = 0; i < 4; i++)
#pragma unroll
        for (int r = 0; r < 4; r++)
          red[wave & 1][wm + i * 16 + fq * 4 + r] = rsum[i][r];
    __syncthreads();
    float* lr = (path ? l_pe : l_se) + b * 128;
    if (t < 128) atomicAdd(&lr[t], red[0][t] + red[1][t]);
  }
}

// ---------------------------------------------------------------------------
// Kernel 5: finish se/pe colsum: wsum[b,k] += sum_q Sc[b,q,k] / l[b,q].
// ---------------------------------------------------------------------------
__global__ __launch_bounds__(256) void colsum2(
    const float* __restrict__ Sc_se, const float* __restrict__ Sc_pe,
    const float* __restrict__ l_se, const float* __restrict__ l_pe,
    float* __restrict__ wsum_se, float* __restrict__ wsum_pe)
{
  __shared__ float inv[32];
  const int f = blockIdx.x, t = threadIdx.x;
  const int path = f >> 7, l = f & 127, b = l & 31, qc = l >> 5;
  const float* Sc = (path ? Sc_pe : Sc_se) + (size_t)b * 65536 + (size_t)(qc * 32) * 512;
  const float* lv = (path ? l_pe : l_se) + b * 128 + qc * 32;
  float* ws = (path ? wsum_pe : wsum_se) + b * 512;
  if (t < 32) inv[t] = 1.f / lv[t];
  __syncthreads();
  float a0 = 0.f, a1 = 0.f;
  for (int q = 0; q < 32; q++) {
    const float iq = inv[q];
    a0 += Sc[(size_t)q * 512 + t] * iq;
    a1 += Sc[(size_t)q * 512 + 256 + t] * iq;
  }
  atomicAdd(&ws[t], a0);
  atomicAdd(&ws[t + 256], a1);
}

// ---------------------------------------------------------------------------
// Kernel 6: wx = wsum @ X_kv (bf16 X). Grid 384.
// ---------------------------------------------------------------------------
__global__ __launch_bounds__(256) void wx_fused(
    const float* __restrict__ wsum_se, const float* __restrict__ wsum_pe,
    const float* __restrict__ wsum_es, const float* __restrict__ wsum_ep,
    const ushort* __restrict__ enz_b, const ushort* __restrict__ sub_b,
    const ushort* __restrict__ prod_b,
    float* __restrict__ wx_se, float* __restrict__ wx_pe,
    float* __restrict__ wx_es, float* __restrict__ wx_ep)
{
  __shared__ float wse[256], wpe[256];
  const int f = blockIdx.x, t = threadIdx.x;
  if (f < 320) {
    const int ch = f % 5, tmp = f / 5, b = tmp & 31, kh = tmp >> 5;
    wse[t] = wsum_se[b * 512 + kh * 256 + t];
    wpe[t] = wsum_pe[b * 512 + kh * 256 + t];
    __syncthreads();
    const int c = ch * 256 + t;
    const ushort* X = enz_b + (size_t)b * 512 * 1280 + (size_t)(kh * 256) * 1280 + c;
    float a_se = 0.f, a_pe = 0.f;
    for (int k = 0; k < 256; k++) {
      const float x = bf2f(X[(size_t)k * 1280]);
      a_se += wse[k] * x;
      a_pe += wpe[k] * x;
    }
    atomicAdd(&wx_se[b * 1280 + c], a_se);
    atomicAdd(&wx_pe[b * 1280 + c], a_pe);
  } else if (f < 352) {
    const int b = f - 320;
    const ushort* X = sub_b + (size_t)b * 128 * 256 + t;
    float a = 0.f;
    for (int k = 0; k < 128; k++) a += wsum_es[b * 128 + k] * bf2f(X[(size_t)k * 256]);
    wx_es[b * 256 + t] = a;
  } else {
    const int b = f - 352;
    const ushort* X = prod_b + (size_t)b * 128 * 256 + t;
    float a = 0.f;
    for (int k = 0; k < 128; k++) a += wsum_ep[b * 128 + k] * bf2f(X[(size_t)k * 256]);
    wx_ep[b * 256 + t] = a;
  }
}

// ---------------------------------------------------------------------------
// Kernel 7: out += inv * (wx chunk @ Wv chunk), c-split for occupancy.
// Grid 96: [0,40) se, [40,80) pe, [80,88) es, [88,96) ep.
// Block = (n-slab of 256) x (c-chunk of 64); 32 per-batch accs in VGPRs;
// wx chunk staged in LDS (broadcast reads). Bias pre-folded into out by prep.
// ---------------------------------------------------------------------------
__global__ __launch_bounds__(256) void out_gemv(
    const float* __restrict__ wx_es, const float* __restrict__ wx_se,
    const float* __restrict__ wx_ep, const float* __restrict__ wx_pe,
    const float* __restrict__ enz_Wv, const float* __restrict__ sub_Wv,
    const float* __restrict__ prod_Wv,
    float* __restrict__ out)
{
  __shared__ float sw[32][64];
  const int f = blockIdx.x, t = threadIdx.x;
  const float* wx; const float* Wv; int Cdim, qoff, nb, cc; float inv;
  if (f < 40)      { wx = wx_se; Wv = sub_Wv;  Cdim = 1280; inv = 1.f / 128.f; qoff = 512;  nb = f & 1;        cc = f >> 1; }
  else if (f < 80) { wx = wx_pe; Wv = prod_Wv; Cdim = 1280; inv = 1.f / 128.f; qoff = 1536; nb = (f - 40) & 1; cc = (f - 40) >> 1; }
  else if (f < 88) { wx = wx_es; Wv = enz_Wv;  Cdim = 256;  inv = 1.f / 512.f; qoff = 0;    nb = (f - 80) & 1; cc = (f - 80) >> 1; }
  else             { wx = wx_ep; Wv = enz_Wv;  Cdim = 256;  inv = 1.f / 512.f; qoff = 1024; nb = (f - 88) & 1; cc = (f - 88) >> 1; }
  const int c0 = cc * 64, n = nb * 256 + t;
#pragma unroll
  for (int i = 0; i < 8; i++) {
    const int idx = t + i * 256, b = idx >> 6, c = idx & 63;
    sw[b][c] = wx[(size_t)b * Cdim + c0 + c];
  }
  __syncthreads();
  float acc[32];
#pragma unroll
  for (int b = 0; b < 32; b++) acc[b] = 0.f;
  for (int c = 0; c < 64; c += 4) {
    const float w0 = Wv[(size_t)(c0 + c) * 512 + n];
    const float w1 = Wv[(size_t)(c0 + c + 1) * 512 + n];
    const float w2 = Wv[(size_t)(c0 + c + 2) * 512 + n];
    const float w3 = Wv[(size_t)(c0 + c + 3) * 512 + n];
#pragma unroll
    for (int b = 0; b < 32; b++) {
      const float4 s = *(const float4*)&sw[b][c];
      acc[b] += s.x * w0 + s.y * w1 + s.z * w2 + s.w * w3;
    }
  }
#pragma unroll
  for (int b = 0; b < 32; b++)
    atomicAdd(&out[(size_t)b * 2048 + qoff + n], acc[b] * inv);
}

// ---------------------------------------------------------------------------
extern "C" void kernel_launch(void* const* d_in, const int* in_sizes, int n_in,
                              void* d_out, int out_size, void* d_ws, size_t ws_size,
                              hipStream_t stream)
{
  (void)in_sizes; (void)n_in; (void)out_size; (void)ws_size;
  const float* enz     = (const float*)d_in[0];   // [32,512,1280]
  const float* sub     = (const float*)d_in[1];   // [32,128,256]
  const float* prod    = (const float*)d_in[2];   // [32,128,256]
  const float* iw      = (const float*)d_in[6];   // [32,128,512]
  const float* enz_Wq  = (const float*)d_in[7];
  const float* enz_bq  = (const float*)d_in[8];
  const float* enz_Wk  = (const float*)d_in[9];
  const float* enz_Wv  = (const float*)d_in[11];
  const float* enz_bv  = (const float*)d_in[12];
  const float* sub_Wq  = (const float*)d_in[13];
  const float* sub_bq  = (const float*)d_in[14];
  const float* sub_Wk  = (const float*)d_in[15];
  const float* sub_Wv  = (const float*)d_in[17];
  const float* sub_bv  = (const float*)d_in[18];
  const float* prod_Wq = (const float*)d_in[19];
  const float* prod_bq = (const float*)d_in[20];
  const float* prod_Wk = (const float*)d_in[21];
  const float* prod_Wv = (const float*)d_in[23];
  const float* prod_bv = (const float*)d_in[24];
  float* out = (float*)d_out;

  char* wsb = (char*)d_ws;
  size_t off = 0;
  auto alloc = [&](size_t bytes) {
    void* p = wsb + off;
    off += (bytes + 255) & ~(size_t)255;
    return p;
  };
  ushort* enz_b   = (ushort*)alloc((size_t)32 * 512 * 1280 * 2);
  ushort* sub_b   = (ushort*)alloc((size_t)32 * 128 * 256 * 2);
  ushort* prod_b  = (ushort*)alloc((size_t)32 * 128 * 256 * 2);
  ushort* eWq_b   = (ushort*)alloc((size_t)1280 * 512 * 2);
  ushort* sWk_b   = (ushort*)alloc((size_t)1280 * 512 * 2);
  ushort* pWk_b   = (ushort*)alloc((size_t)1280 * 512 * 2);
  ushort* eWk_b   = (ushort*)alloc((size_t)256 * 512 * 2);
  ushort* sWq_b   = (ushort*)alloc((size_t)256 * 512 * 2);
  ushort* pWq_b   = (ushort*)alloc((size_t)256 * 512 * 2);
  ushort* W3t     = (ushort*)alloc((size_t)896 * 1280 * 2);
  ushort* Y       = (ushort*)alloc((size_t)16384 * 896 * 2);
  float*  u_e_s   = (float*)alloc(256 * 4);
  float*  Sc_se   = (float*)alloc((size_t)32 * 128 * 512 * 4);
  float*  Sc_pe   = (float*)alloc((size_t)32 * 128 * 512 * 4);
  // zero region (contiguous; sizes are 256B multiples): 147456 floats total
  float* wsum_es = (float*)alloc(4096 * 4);
  float* wsum_ep = (float*)alloc(4096 * 4);
  float* wsum_se = (float*)alloc(16384 * 4);
  float* wsum_pe = (float*)alloc(16384 * 4);
  float* l_se    = (float*)alloc(4096 * 4);
  float* l_pe    = (float*)alloc(4096 * 4);
  float* wx_se   = (float*)alloc(40960 * 4);
  float* wx_pe   = (float*)alloc(40960 * 4);
  float* wx_es   = (float*)alloc(8192 * 4);
  float* wx_ep   = (float*)alloc(8192 * 4);

  const dim3 blk(256);

  prep_fused<<<13739, blk, 0, stream>>>(
      enz, sub, prod, enz_b, sub_b, prod_b,
      enz_Wq, enz_Wk, sub_Wq, sub_Wk, prod_Wq, prod_Wk,
      eWq_b, eWk_b, sWq_b, sWk_b, pWq_b, pWk_b,
      enz_bq, sub_bq, prod_bq, enz_bv, sub_bv, prod_bv,
      W3t, u_e_s, wsum_es, out);

  fold_w3<<<60, blk, 0, stream>>>(eWq_b, eWk_b, sWq_b, sWk_b, pWq_b, pWk_b, W3t);

  y_gemm<<<896, blk, 0, stream>>>(enz_b, W3t, Y);

  score_fused<<<512, blk, 0, stream>>>(
      Y, sub_b, prod_b, iw, u_e_s, Sc_se, Sc_pe, l_se, l_pe, wsum_es, wsum_ep);

  colsum2<<<256, blk, 0, stream>>>(Sc_se, Sc_pe, l_se, l_pe, wsum_se, wsum_pe);

  wx_fused<<<384, blk, 0, stream>>>(
      wsum_se, wsum_pe, wsum_es, wsum_ep, enz_b, sub_b, prod_b,
      wx_se, wx_pe, wx_es, wx_ep);

  out_gemv<<<96, blk, 0, stream>>>(
      wx_es, wx_se, wx_ep, wx_pe, enz_Wv, sub_Wv, prod_Wv, out);
}

// Round 3
// 313.106 us; speedup vs baseline: 1.3287x; 1.0646x over previous
//
#include <hip/hip_runtime.h>
#include <cstdint>
#include <cstddef>

// ---------------------------------------------------------------------------
// EnzymeCompoundCrossAttention — R6: 256^2 counted-vmcnt y_gemm (T2+T3+T4+T5).
//
// Algebra (R1/R2/R4 verified):
//   score = x_q (Wq Wk^T) x_k^T / S + (x_k . (Wk bq)) / S   (+iw bias; bk and
//   q-constant terms cancel in softmax).
//   All big GEMMs collapse into Y = enz @ W3, W3t padded to [1024 x 1280]:
//   rows [0,256)=M_big^T, [256,512)=M_se, [512,768)=M_pe, 768/769=u_s,u_p,
//   [770,1024)=0.  Y stride 1024. Score GEMMs contract over d_cpd=256.
//   out_quarter = (1/Lq) * (wsum @ X_kv) @ Wv + bv.
// R6: y_gemm rewritten: BM=BN=256 BK=64, 8 waves/512thr, 128KiB dbuf LDS,
//   XOR-swizzle (T2, both-sides), counted vmcnt(4) boundaries (T3/T4),
//   setprio around MFMA clusters (T5). Grid 256 = 1 block/CU.
// Launches: prep -> fold -> y_gemm -> score -> colsum2 -> wx -> out (7).
// ---------------------------------------------------------------------------

#define SCALE_INV 0.044194173824159216f  // 1/sqrt(512)

typedef short bf16x8 __attribute__((ext_vector_type(8)));
typedef float f32x4  __attribute__((ext_vector_type(4)));

__device__ __forceinline__ ushort f2bf(float f) {
  union { float f; unsigned u; } c; c.f = f;
  unsigned u = c.u + 0x7fffu + ((c.u >> 16) & 1u);
  return (ushort)(u >> 16);
}
__device__ __forceinline__ float bf2f(ushort h) {
  return __uint_as_float(((unsigned)h) << 16);
}
__device__ __forceinline__ void gload16(const ushort* g, ushort* l) {
  __builtin_amdgcn_global_load_lds(
      (const __attribute__((address_space(1))) void*)g,
      (__attribute__((address_space(3))) void*)l, 16, 0, 0);
}

// ---------------------------------------------------------------------------
// Kernel 1: prep — segmented flat grid. Grid 14059.
//   [0,10240)      cvt enz f32->bf16 (20,971,520 elems, 8/thread)
//   [10240,10752)  cvt sub (1,048,576)
//   [10752,11264)  cvt prod
//   [11264,12416)  cvt 6 weight mats to bf16 (natural layout, no transpose)
//   [12416,12592)  u vectors: u_s,u_p -> W3t rows 768/769 (bf16);
//                  u_e * SCALE_INV -> f32[256]
//   [12592,13168)  zero 147456 floats (wsum/l/wx region)
//   [13168,13803)  zero W3t rows 770..1023 (162560 uints)
//   [13803,14059)  out init = bias (65536 floats; out_gemv atomicAdds later)
// ---------------------------------------------------------------------------
__device__ __forceinline__ void cvt8(const float* __restrict__ in,
                                     ushort* __restrict__ out, int blk, int n) {
  int i = (blk * 256 + (int)threadIdx.x) * 8;
  if (i >= n) return;
  float4 a = *(const float4*)(in + i);
  float4 b = *(const float4*)(in + i + 4);
  ushort o[8] = { f2bf(a.x), f2bf(a.y), f2bf(a.z), f2bf(a.w),
                  f2bf(b.x), f2bf(b.y), f2bf(b.z), f2bf(b.w) };
  *(uint4*)(out + i) = *(uint4*)o;
}

__global__ __launch_bounds__(256) void prep_fused(
    const float* __restrict__ enz, const float* __restrict__ sub,
    const float* __restrict__ prod,
    ushort* __restrict__ enz_b, ushort* __restrict__ sub_b, ushort* __restrict__ prod_b,
    const float* __restrict__ enz_Wq, const float* __restrict__ enz_Wk,
    const float* __restrict__ sub_Wq, const float* __restrict__ sub_Wk,
    const float* __restrict__ prod_Wq, const float* __restrict__ prod_Wk,
    ushort* __restrict__ eWq_b, ushort* __restrict__ eWk_b,
    ushort* __restrict__ sWq_b, ushort* __restrict__ sWk_b,
    ushort* __restrict__ pWq_b, ushort* __restrict__ pWk_b,
    const float* __restrict__ enz_bq, const float* __restrict__ sub_bq,
    const float* __restrict__ prod_bq,
    const float* __restrict__ enz_bv, const float* __restrict__ sub_bv,
    const float* __restrict__ prod_bv,
    ushort* __restrict__ W3t, float* __restrict__ u_e_s,
    float* __restrict__ zero_base, float* __restrict__ out)
{
  const int f = blockIdx.x, t = threadIdx.x;
  if (f < 10240) { cvt8(enz, enz_b, f, 20971520); return; }
  if (f < 10752) { cvt8(sub, sub_b, f - 10240, 1048576); return; }
  if (f < 11264) { cvt8(prod, prod_b, f - 10752, 1048576); return; }
  if (f < 12416) {
    const int l = f - 11264;
    if (l < 320)       cvt8(enz_Wq,  eWq_b, l,        655360);
    else if (l < 640)  cvt8(sub_Wk,  sWk_b, l - 320,  655360);
    else if (l < 960)  cvt8(prod_Wk, pWk_b, l - 640,  655360);
    else if (l < 1024) cvt8(enz_Wk,  eWk_b, l - 960,  131072);
    else if (l < 1088) cvt8(sub_Wq,  sWq_b, l - 1024, 131072);
    else               cvt8(prod_Wq, pWq_b, l - 1088, 131072);
    return;
  }
  if (f < 12592) {
    // u[d] = dot(Wk[d,:512], bq). 16 rows/block, 16 threads/row.
    const int g = f - 12416;
    const float* W; const float* bv; int d0, kind;
    if (g < 80)       { W = sub_Wk;  bv = sub_bq;  d0 = g * 16;         kind = 0; }
    else if (g < 160) { W = prod_Wk; bv = prod_bq; d0 = (g - 80) * 16;  kind = 1; }
    else              { W = enz_Wk;  bv = enz_bq;  d0 = (g - 160) * 16; kind = 2; }
    const int r = t >> 4, i = t & 15, d = d0 + r;
    const float* row = W + (size_t)d * 512;
    float s = 0.f;
#pragma unroll
    for (int j = 0; j < 32; j++) s += row[i + j * 16] * bv[i + j * 16];
    s += __shfl_xor(s, 1); s += __shfl_xor(s, 2);
    s += __shfl_xor(s, 4); s += __shfl_xor(s, 8);
    if (i == 0) {
      if (kind < 2) W3t[(size_t)(768 + kind) * 1280 + d] = f2bf(s);
      else          u_e_s[d] = s * SCALE_INV;
    }
    return;
  }
  if (f < 13168) { zero_base[(f - 12592) * 256 + t] = 0.f; return; }
  if (f < 13803) {
    const int idx = (f - 13168) * 256 + t;  // < 162560
    ((unsigned*)(W3t + (size_t)770 * 1280))[idx] = 0u;
    return;
  }
  {
    const int idx = (f - 13803) * 256 + t;  // < 65536 = 32*2048
    const int col = idx & 2047;
    const int q = col >> 9, n = col & 511;
    const float* bvp = (q == 1) ? sub_bv : (q == 3) ? prod_bv : enz_bv;
    out[idx] = bvp[n];
  }
}

// ---------------------------------------------------------------------------
// MFMA tile core (128x128, 2-barrier, used by fold_w3 / score_fused).
// ---------------------------------------------------------------------------
__device__ __forceinline__ void mfma_tile(
    const ushort* __restrict__ A, int lda,
    const ushort* __restrict__ Bt, int ldb, int K,
    int bm, int bn, ushort* AsBase, ushort* BsBase, f32x4 (&acc)[4][4])
{
  const int t = threadIdx.x, wave = t >> 6, lane = t & 63;
  const int srow = wave * 16 + (lane >> 2);
  const int sseg = (lane & 3) * 8;
  const ushort* Ag0 = A + (size_t)(bm + srow) * lda + sseg;
  const ushort* Ag1 = Ag0 + (size_t)64 * lda;
  const ushort* Bg0 = Bt + (size_t)(bn + srow) * ldb + sseg;
  const ushort* Bg1 = Bg0 + (size_t)64 * ldb;
  ushort* AsP0 = AsBase + srow * 32 + sseg;
  ushort* AsP1 = AsP0 + 64 * 32;
  ushort* BsP0 = BsBase + srow * 32 + sseg;
  ushort* BsP1 = BsP0 + 64 * 32;
  const int wm = (wave >> 1) * 64, wn = (wave & 1) * 64;
  const int fl = lane & 15, fq = lane >> 4;
  const bf16x8* ArP = (const bf16x8*)(AsBase + (wm + fl) * 32 + fq * 8);
  const bf16x8* BrP = (const bf16x8*)(BsBase + (wn + fl) * 32 + fq * 8);
  for (int k0 = 0; k0 < K; k0 += 32) {
    __syncthreads();
    gload16(Ag0 + k0, AsP0);
    gload16(Ag1 + k0, AsP1);
    gload16(Bg0 + k0, BsP0);
    gload16(Bg1 + k0, BsP1);
    __syncthreads();
    bf16x8 af[4], bfr[4];
#pragma unroll
    for (int i = 0; i < 4; i++) af[i] = ArP[i * 64];
#pragma unroll
    for (int j = 0; j < 4; j++) bfr[j] = BrP[j * 64];
#pragma unroll
    for (int i = 0; i < 4; i++)
#pragma unroll
      for (int j = 0; j < 4; j++)
        acc[i][j] = __builtin_amdgcn_mfma_f32_16x16x32_bf16(af[i], bfr[j], acc[i][j], 0, 0, 0);
  }
}

// ---------------------------------------------------------------------------
// Kernel 2: fold — W3t rows 0..767 via 3 MFMA GEMMs, K=512. Grid 60.
// ---------------------------------------------------------------------------
__global__ __launch_bounds__(256) void fold_w3(
    const ushort* __restrict__ eWq_b, const ushort* __restrict__ eWk_b,
    const ushort* __restrict__ sWq_b, const ushort* __restrict__ sWk_b,
    const ushort* __restrict__ pWq_b, const ushort* __restrict__ pWk_b,
    ushort* __restrict__ W3t)
{
  __shared__ __align__(16) ushort As[128 * 32];
  __shared__ __align__(16) ushort Bs[128 * 32];
  const int f = blockIdx.x, seg = f / 20, l = f % 20;
  const int bm = (l / 10) * 128, bn = (l % 10) * 128;
  const ushort* A  = (seg == 0) ? eWk_b : (seg == 1) ? sWq_b : pWq_b;
  const ushort* Bt = (seg == 0) ? eWq_b : (seg == 1) ? sWk_b : pWk_b;
  f32x4 acc[4][4] = {};
  mfma_tile(A, 512, Bt, 512, 512, bm, bn, As, Bs, acc);
  const int lane = threadIdx.x & 63, wave = threadIdx.x >> 6;
  const int wm = (wave >> 1) * 64, wn = (wave & 1) * 64;
  const int fl = lane & 15, fq = lane >> 4;
#pragma unroll
  for (int i = 0; i < 4; i++)
#pragma unroll
    for (int j = 0; j < 4; j++) {
      const int col = bn + wn + j * 16 + fl;
#pragma unroll
      for (int r = 0; r < 4; r++) {
        const int row = seg * 256 + bm + wm + i * 16 + fq * 4 + r;
        W3t[(size_t)row * 1280 + col] = f2bf(acc[i][j][r]);
      }
    }
}

// ---------------------------------------------------------------------------
// Kernel 3: Y = enz @ W3  (M=16384, N=1024 padded, K=1280).
// 256x256 tile, BK=64, 512 thr / 8 waves (2M x 4N), dbuf 128 KiB LDS.
// T2: XOR-swizzle byte^=((row&7)<<4), both-sides (inverse-swz global source,
//     swz ds_read).  T3/T4: raw barriers + counted vmcnt(4) (never 0 in
//     steady loop).  T5: setprio around MFMA clusters.
// Grid 256 (=1 block/CU), XCD swizzle: xcd=f&7 owns 8 m-tiles.
// N-tile 3 (bn=768): only cols 768/769 needed -> waves skip unneeded frags.
// ---------------------------------------------------------------------------
__device__ __forceinline__ void yg_stage_half(
    const ushort* __restrict__ gbase, int k0, int h,
    ushort* ldsTile, int wv, int l, int srow8, int scol)
{
  const int row0 = h * 128 + wv * 16 + srow8;
  const ushort* g0 = gbase + (size_t)row0 * 1280 + k0 + scol;
  ushort* d0 = ldsTile + h * 8192 + wv * 1024 + l * 8;
  gload16(g0, d0);
  gload16(g0 + (size_t)8 * 1280, d0 + 512);
}

__device__ __forceinline__ bf16x8 yg_frag(const ushort* tile, int row, int kk, int fq) {
  const int X = (kk * 64 + fq * 16) ^ ((row & 7) << 4);
  return *(const bf16x8*)((const char*)tile + row * 128 + X);
}

__global__ __launch_bounds__(512, 2) void y_gemm(
    const ushort* __restrict__ A,      // enz_b [16384][1280]
    const ushort* __restrict__ B,      // W3t   [1024][1280]
    ushort* __restrict__ Y)            // [16384][1024]
{
  extern __shared__ __align__(16) ushort lds[];   // 2 bufs x (A 16384 | B 16384)
  const int t = threadIdx.x;
  const int wv = t >> 6, l = t & 63;
  const int fl = l & 15, fq = l >> 4;
  const int f = blockIdx.x;
  const int xcd = f & 7, slot = f >> 3;
  const int mt = xcd * 8 + (slot >> 2), nt = slot & 3;
  const int bm = mt * 256, bn = nt * 256;
  const int wm = (wv >> 2) * 128, wn = (wv & 3) * 64;
  const int nfr = (bn != 768) ? 4 : (((wv & 3) == 0) ? 1 : 0);
  const int srow8 = l >> 3;
  const int scol = 8 * ((l & 7) ^ srow8);     // inverse-swizzled source col
  const ushort* Ag = A + (size_t)bm * 1280;
  const ushort* Bg = B + (size_t)bn * 1280;

  f32x4 acc[8][4] = {};

  // ---- prologue: tile0 (buf0) fully + tile1 A-halves (buf1) ----
  yg_stage_half(Ag, 0, 0, lds, wv, l, srow8, scol);
  yg_stage_half(Ag, 0, 1, lds, wv, l, srow8, scol);
  yg_stage_half(Bg, 0, 0, lds + 16384, wv, l, srow8, scol);
  yg_stage_half(Bg, 0, 1, lds + 16384, wv, l, srow8, scol);
  yg_stage_half(Ag, 64, 0, lds + 32768, wv, l, srow8, scol);
  yg_stage_half(Ag, 64, 1, lds + 32768, wv, l, srow8, scol);
  asm volatile("s_waitcnt vmcnt(4)" ::: "memory");
  __builtin_amdgcn_s_barrier();
  __builtin_amdgcn_sched_barrier(0);

  for (int j = 0; j < 20; ++j) {
    const int p = j & 1;
    const ushort* At = lds + p * 32768;
    const ushort* Bt = At + 16384;
    ushort* Ao = (ushort*)(lds + (p ^ 1) * 32768);
    ushort* Bo = Ao + 16384;
    const int kn = (j + 1) * 64;

    // PH0: stage next B-half0; read B-frags; A-pair 0 + MFMA
    if (j < 19) yg_stage_half(Bg, kn, 0, Bo, wv, l, srow8, scol);
    bf16x8 bf_[4][2];
    if (nfr > 0) {
#pragma unroll
      for (int n = 0; n < 4; ++n) if (n < nfr)
#pragma unroll
        for (int kk = 0; kk < 2; ++kk)
          bf_[n][kk] = yg_frag(Bt, wn + n * 16 + fl, kk, fq);
    }
#pragma unroll
    for (int mp = 0; mp < 4; ++mp) {
      if (mp == 1 && j < 19) yg_stage_half(Bg, kn, 1, Bo, wv, l, srow8, scol);
      if (nfr > 0) {
        bf16x8 a0[2], a1[2];
#pragma unroll
        for (int kk = 0; kk < 2; ++kk) {
          a0[kk] = yg_frag(At, wm + (mp * 2) * 16 + fl, kk, fq);
          a1[kk] = yg_frag(At, wm + (mp * 2 + 1) * 16 + fl, kk, fq);
        }
        __builtin_amdgcn_s_setprio(1);
#pragma unroll
        for (int n = 0; n < 4; ++n) if (n < nfr) {
#pragma unroll
          for (int kk = 0; kk < 2; ++kk) {
            acc[mp * 2][n] = __builtin_amdgcn_mfma_f32_16x16x32_bf16(
                a0[kk], bf_[n][kk], acc[mp * 2][n], 0, 0, 0);
            acc[mp * 2 + 1][n] = __builtin_amdgcn_mfma_f32_16x16x32_bf16(
                a1[kk], bf_[n][kk], acc[mp * 2 + 1][n], 0, 0, 0);
          }
        }
        __builtin_amdgcn_s_setprio(0);
      }
    }

    // ---- boundary: release buf p, stage A(j+2) into it, counted wait ----
    asm volatile("" ::: "memory");
    __builtin_amdgcn_s_barrier();
    if (j + 2 < 20) {
      yg_stage_half(Ag, (j + 2) * 64, 0, (ushort*)At, wv, l, srow8, scol);
      yg_stage_half(Ag, (j + 2) * 64, 1, (ushort*)At, wv, l, srow8, scol);
    }
    if (j < 18) asm volatile("s_waitcnt vmcnt(4)" ::: "memory");
    else        asm volatile("s_waitcnt vmcnt(0)" ::: "memory");
    __builtin_amdgcn_s_barrier();
    __builtin_amdgcn_sched_barrier(0);
  }

  // ---- epilogue: C-write ----
#pragma unroll
  for (int m = 0; m < 8; ++m)
#pragma unroll
    for (int n = 0; n < 4; ++n) if (n < nfr) {
#pragma unroll
      for (int r = 0; r < 4; ++r) {
        const int row = bm + wm + m * 16 + fq * 4 + r;
        const int col = bn + wn + n * 16 + fl;
        Y[(size_t)row * 1024 + col] = f2bf(acc[m][n][r]);
      }
    }
}

// ---------------------------------------------------------------------------
// Kernel 4: all 4 score GEMMs + softmax plumbing. Grid 512. K=256.
// Y stride = 1024 now.
// ---------------------------------------------------------------------------
__global__ __launch_bounds__(256) void score_fused(
    const ushort* __restrict__ Y, const ushort* __restrict__ sub_b,
    const ushort* __restrict__ prod_b, const float* __restrict__ iw,
    const float* __restrict__ u_e_s,
    float* __restrict__ Sc_se, float* __restrict__ Sc_pe,
    float* __restrict__ l_se, float* __restrict__ l_pe,
    float* __restrict__ wsum_es, float* __restrict__ wsum_ep)
{
  __shared__ __align__(16) ushort As[128 * 32];
  __shared__ __align__(16) ushort Bs[128 * 32];
  __shared__ float red[2][128];
  __shared__ float red2[2][128];
  __shared__ float tsh[128];
  const int f = blockIdx.x, t = threadIdx.x;
  const int lane = t & 63, wave = t >> 6;
  const int wm = (wave >> 1) * 64, wn = (wave & 1) * 64;
  const int fl = lane & 15, fq = lane >> 4;
  f32x4 acc[4][4] = {};

  if (f < 256) {
    // ---- es / ep ----
    const int path = f >> 7, l = f & 127, b = l & 31, mt = l >> 5;
    const int bm = mt * 128;
    const ushort* X = (path ? prod_b : sub_b) + (size_t)b * 32768;
    {   // tsh[k] = SCALE_INV * dot(X[k,:], u_e)  (u_e_s pre-scaled)
      const int col = t >> 1, half = t & 1;
      const ushort* xr = X + col * 256 + half * 128;
      const float* uu = u_e_s + half * 128;
      float s = 0.f;
      for (int c = 0; c < 128; c++) s += bf2f(xr[c]) * uu[c];
      s += __shfl_xor(s, 1);
      if (!half) tsh[col] = s;
    }   // mfma_tile's first __syncthreads orders tsh for all readers
    mfma_tile(Y + (size_t)b * 512 * 1024, 1024, X, 256, 256, bm, 0, As, Bs, acc);
    const size_t ib = (size_t)b * 65536;
    float rsum[4][4];
#pragma unroll
    for (int i = 0; i < 4; i++)
#pragma unroll
      for (int r = 0; r < 4; r++) rsum[i][r] = 0.f;
#pragma unroll
    for (int i = 0; i < 4; i++)
#pragma unroll
      for (int j = 0; j < 4; j++)
#pragma unroll
        for (int r = 0; r < 4; r++) {
          const int row = wm + i * 16 + fq * 4 + r;   // local q
          const int col = wn + j * 16 + fl;           // k (global, bn=0)
          float s = acc[i][j][r] * SCALE_INV + tsh[col];
          if (path == 0) s += iw[ib + (size_t)col * 512 + (bm + row)];
          const float e = __expf(s);
          acc[i][j][r] = e;
          rsum[i][r] += e;
        }
#pragma unroll
    for (int m = 1; m <= 8; m <<= 1)
#pragma unroll
      for (int i = 0; i < 4; i++)
#pragma unroll
        for (int r = 0; r < 4; r++)
          rsum[i][r] += __shfl_xor(rsum[i][r], m);
    if (fl == 0)
#pragma unroll
      for (int i = 0; i < 4; i++)
#pragma unroll
        for (int r = 0; r < 4; r++)
          red[wave & 1][wm + i * 16 + fq * 4 + r] = rsum[i][r];
    __syncthreads();
    float csum[4] = { 0.f, 0.f, 0.f, 0.f };
#pragma unroll
    for (int i = 0; i < 4; i++)
#pragma unroll
      for (int r = 0; r < 4; r++) {
        const int row = wm + i * 16 + fq * 4 + r;
        const float invr = 1.f / (red[0][row] + red[1][row]);
#pragma unroll
        for (int j = 0; j < 4; j++) csum[j] += acc[i][j][r] * invr;
      }
#pragma unroll
    for (int m = 16; m <= 32; m <<= 1)
#pragma unroll
      for (int j = 0; j < 4; j++) csum[j] += __shfl_xor(csum[j], m);
    if (fq == 0)
#pragma unroll
      for (int j = 0; j < 4; j++) red2[wave >> 1][wn + j * 16 + fl] = csum[j];
    __syncthreads();
    float* ws = (path ? wsum_ep : wsum_es) + b * 128;
    if (t < 128) atomicAdd(&ws[t], red2[0][t] + red2[1][t]);
  } else {
    // ---- se / pe ----
    const int g = f - 256, path = g >> 7, l = g & 127, b = l & 31, nt = l >> 5;
    const int bn = nt * 128;
    const ushort* A  = (path ? prod_b : sub_b) + (size_t)b * 32768;
    const ushort* Bt = Y + (size_t)b * 512 * 1024 + 256 + path * 256;
    mfma_tile(A, 256, Bt, 1024, 256, 0, bn, As, Bs, acc);
    const size_t ib = (size_t)b * 65536;
    float* Sc = (path ? Sc_pe : Sc_se) + ib;
    float tv[4];
#pragma unroll
    for (int j = 0; j < 4; j++) {
      const int col = wn + j * 16 + fl;
      tv[j] = bf2f(Y[(size_t)(b * 512 + bn + col) * 1024 + 768 + path]) * SCALE_INV;
    }
    float rsum[4][4];
#pragma unroll
    for (int i = 0; i < 4; i++)
#pragma unroll
      for (int r = 0; r < 4; r++) rsum[i][r] = 0.f;
#pragma unroll
    for (int i = 0; i < 4; i++)
#pragma unroll
      for (int j = 0; j < 4; j++)
#pragma unroll
        for (int r = 0; r < 4; r++) {
          const int row = wm + i * 16 + fq * 4 + r;   // q (global, bm=0)
          const int col = wn + j * 16 + fl;           // local k
          float s = acc[i][j][r] * SCALE_INV + tv[j];
          if (path == 0) s += iw[ib + (size_t)row * 512 + (bn + col)];
          const float e = __expf(s);
          Sc[(size_t)row * 512 + bn + col] = e;
          rsum[i][r] += e;
        }
#pragma unroll
    for (int m = 1; m <= 8; m <<= 1)
#pragma unroll
      for (int i = 0; i < 4; i++)
#pragma unroll
        for (int r = 0; r < 4; r++)
          rsum[i][r] += __shfl_xor(rsum[i][r], m);
    if (fl == 0)
#pragma unroll
      for (int i = 0; i < 4; i++)
#pragma unroll
        for (int r = 0; r < 4; r++)
          red[wave & 1][wm + i * 16 + fq * 4 + r] = rsum[i][r];
    __syncthreads();
    float* lr = (path ? l_pe : l_se) + b * 128;
    if (t < 128) atomicAdd(&lr[t], red[0][t] + red[1][t]);
  }
}

// ---------------------------------------------------------------------------
// Kernel 5: finish se/pe colsum: wsum[b,k] += sum_q Sc[b,q,k] / l[b,q].
// ---------------------------------------------------------------------------
__global__ __launch_bounds__(256) void colsum2(
    const float* __restrict__ Sc_se, const float* __restrict__ Sc_pe,
    const float* __restrict__ l_se, const float* __restrict__ l_pe,
    float* __restrict__ wsum_se, float* __restrict__ wsum_pe)
{
  __shared__ float inv[32];
  const int f = blockIdx.x, t = threadIdx.x;
  const int path = f >> 7, l = f & 127, b = l & 31, qc = l >> 5;
  const float* Sc = (path ? Sc_pe : Sc_se) + (size_t)b * 65536 + (size_t)(qc * 32) * 512;
  const float* lv = (path ? l_pe : l_se) + b * 128 + qc * 32;
  float* ws = (path ? wsum_pe : wsum_se) + b * 512;
  if (t < 32) inv[t] = 1.f / lv[t];
  __syncthreads();
  float a0 = 0.f, a1 = 0.f;
  for (int q = 0; q < 32; q++) {
    const float iq = inv[q];
    a0 += Sc[(size_t)q * 512 + t] * iq;
    a1 += Sc[(size_t)q * 512 + 256 + t] * iq;
  }
  atomicAdd(&ws[t], a0);
  atomicAdd(&ws[t + 256], a1);
}

// ---------------------------------------------------------------------------
// Kernel 6: wx = wsum @ X_kv (bf16 X). Grid 384.
// ---------------------------------------------------------------------------
__global__ __launch_bounds__(256) void wx_fused(
    const float* __restrict__ wsum_se, const float* __restrict__ wsum_pe,
    const float* __restrict__ wsum_es, const float* __restrict__ wsum_ep,
    const ushort* __restrict__ enz_b, const ushort* __restrict__ sub_b,
    const ushort* __restrict__ prod_b,
    float* __restrict__ wx_se, float* __restrict__ wx_pe,
    float* __restrict__ wx_es, float* __restrict__ wx_ep)
{
  __shared__ float wse[256], wpe[256];
  const int f = blockIdx.x, t = threadIdx.x;
  if (f < 320) {
    const int ch = f % 5, tmp = f / 5, b = tmp & 31, kh = tmp >> 5;
    wse[t] = wsum_se[b * 512 + kh * 256 + t];
    wpe[t] = wsum_pe[b * 512 + kh * 256 + t];
    __syncthreads();
    const int c = ch * 256 + t;
    const ushort* X = enz_b + (size_t)b * 512 * 1280 + (size_t)(kh * 256) * 1280 + c;
    float a_se = 0.f, a_pe = 0.f;
    for (int k = 0; k < 256; k++) {
      const float x = bf2f(X[(size_t)k * 1280]);
      a_se += wse[k] * x;
      a_pe += wpe[k] * x;
    }
    atomicAdd(&wx_se[b * 1280 + c], a_se);
    atomicAdd(&wx_pe[b * 1280 + c], a_pe);
  } else if (f < 352) {
    const int b = f - 320;
    const ushort* X = sub_b + (size_t)b * 128 * 256 + t;
    float a = 0.f;
    for (int k = 0; k < 128; k++) a += wsum_es[b * 128 + k] * bf2f(X[(size_t)k * 256]);
    wx_es[b * 256 + t] = a;
  } else {
    const int b = f - 352;
    const ushort* X = prod_b + (size_t)b * 128 * 256 + t;
    float a = 0.f;
    for (int k = 0; k < 128; k++) a += wsum_ep[b * 128 + k] * bf2f(X[(size_t)k * 256]);
    wx_ep[b * 256 + t] = a;
  }
}

// ---------------------------------------------------------------------------
// Kernel 7: out += inv * (wx chunk @ Wv chunk), c-split for occupancy.
// Grid 96. Bias pre-folded into out by prep.
// ---------------------------------------------------------------------------
__global__ __launch_bounds__(256) void out_gemv(
    const float* __restrict__ wx_es, const float* __restrict__ wx_se,
    const float* __restrict__ wx_ep, const float* __restrict__ wx_pe,
    const float* __restrict__ enz_Wv, const float* __restrict__ sub_Wv,
    const float* __restrict__ prod_Wv,
    float* __restrict__ out)
{
  __shared__ float sw[32][64];
  const int f = blockIdx.x, t = threadIdx.x;
  const float* wx; const float* Wv; int Cdim, qoff, nb, cc; float inv;
  if (f < 40)      { wx = wx_se; Wv = sub_Wv;  Cdim = 1280; inv = 1.f / 128.f; qoff = 512;  nb = f & 1;        cc = f >> 1; }
  else if (f < 80) { wx = wx_pe; Wv = prod_Wv; Cdim = 1280; inv = 1.f / 128.f; qoff = 1536; nb = (f - 40) & 1; cc = (f - 40) >> 1; }
  else if (f < 88) { wx = wx_es; Wv = enz_Wv;  Cdim = 256;  inv = 1.f / 512.f; qoff = 0;    nb = (f - 80) & 1; cc = (f - 80) >> 1; }
  else             { wx = wx_ep; Wv = enz_Wv;  Cdim = 256;  inv = 1.f / 512.f; qoff = 1024; nb = (f - 88) & 1; cc = (f - 88) >> 1; }
  const int c0 = cc * 64, n = nb * 256 + t;
#pragma unroll
  for (int i = 0; i < 8; i++) {
    const int idx = t + i * 256, b = idx >> 6, c = idx & 63;
    sw[b][c] = wx[(size_t)b * Cdim + c0 + c];
  }
  __syncthreads();
  float acc[32];
#pragma unroll
  for (int b = 0; b < 32; b++) acc[b] = 0.f;
  for (int c = 0; c < 64; c += 4) {
    const float w0 = Wv[(size_t)(c0 + c) * 512 + n];
    const float w1 = Wv[(size_t)(c0 + c + 1) * 512 + n];
    const float w2 = Wv[(size_t)(c0 + c + 2) * 512 + n];
    const float w3 = Wv[(size_t)(c0 + c + 3) * 512 + n];
#pragma unroll
    for (int b = 0; b < 32; b++) {
      const float4 s = *(const float4*)&sw[b][c];
      acc[b] += s.x * w0 + s.y * w1 + s.z * w2 + s.w * w3;
    }
  }
#pragma unroll
  for (int b = 0; b < 32; b++)
    atomicAdd(&out[(size_t)b * 2048 + qoff + n], acc[b] * inv);
}

// ---------------------------------------------------------------------------
extern "C" void kernel_launch(void* const* d_in, const int* in_sizes, int n_in,
                              void* d_out, int out_size, void* d_ws, size_t ws_size,
                              hipStream_t stream)
{
  (void)in_sizes; (void)n_in; (void)out_size; (void)ws_size;
  const float* enz     = (const float*)d_in[0];   // [32,512,1280]
  const float* sub     = (const float*)d_in[1];   // [32,128,256]
  const float* prod    = (const float*)d_in[2];   // [32,128,256]
  const float* iw      = (const float*)d_in[6];   // [32,128,512]
  const float* enz_Wq  = (const float*)d_in[7];
  const float* enz_bq  = (const float*)d_in[8];
  const float* enz_Wk  = (const float*)d_in[9];
  const float* enz_Wv  = (const float*)d_in[11];
  const float* enz_bv  = (const float*)d_in[12];
  const float* sub_Wq  = (const float*)d_in[13];
  const float* sub_bq  = (const float*)d_in[14];
  const float* sub_Wk  = (const float*)d_in[15];
  const float* sub_Wv  = (const float*)d_in[17];
  const float* sub_bv  = (const float*)d_in[18];
  const float* prod_Wq = (const float*)d_in[19];
  const float* prod_bq = (const float*)d_in[20];
  const float* prod_Wk = (const float*)d_in[21];
  const float* prod_Wv = (const float*)d_in[23];
  const float* prod_bv = (const float*)d_in[24];
  float* out = (float*)d_out;

  char* wsb = (char*)d_ws;
  size_t off = 0;
  auto alloc = [&](size_t bytes) {
    void* p = wsb + off;
    off += (bytes + 255) & ~(size_t)255;
    return p;
  };
  ushort* enz_b   = (ushort*)alloc((size_t)32 * 512 * 1280 * 2);
  ushort* sub_b   = (ushort*)alloc((size_t)32 * 128 * 256 * 2);
  ushort* prod_b  = (ushort*)alloc((size_t)32 * 128 * 256 * 2);
  ushort* eWq_b   = (ushort*)alloc((size_t)1280 * 512 * 2);
  ushort* sWk_b   = (ushort*)alloc((size_t)1280 * 512 * 2);
  ushort* pWk_b   = (ushort*)alloc((size_t)1280 * 512 * 2);
  ushort* eWk_b   = (ushort*)alloc((size_t)256 * 512 * 2);
  ushort* sWq_b   = (ushort*)alloc((size_t)256 * 512 * 2);
  ushort* pWq_b   = (ushort*)alloc((size_t)256 * 512 * 2);
  ushort* W3t     = (ushort*)alloc((size_t)1024 * 1280 * 2);
  ushort* Y       = (ushort*)alloc((size_t)16384 * 1024 * 2);
  float*  u_e_s   = (float*)alloc(256 * 4);
  float*  Sc_se   = (float*)alloc((size_t)32 * 128 * 512 * 4);
  float*  Sc_pe   = (float*)alloc((size_t)32 * 128 * 512 * 4);
  // zero region (contiguous; sizes are 256B multiples): 147456 floats total
  float* wsum_es = (float*)alloc(4096 * 4);
  float* wsum_ep = (float*)alloc(4096 * 4);
  float* wsum_se = (float*)alloc(16384 * 4);
  float* wsum_pe = (float*)alloc(16384 * 4);
  float* l_se    = (float*)alloc(4096 * 4);
  float* l_pe    = (float*)alloc(4096 * 4);
  float* wx_se   = (float*)alloc(40960 * 4);
  float* wx_pe   = (float*)alloc(40960 * 4);
  float* wx_es   = (float*)alloc(8192 * 4);
  float* wx_ep   = (float*)alloc(8192 * 4);

  static bool ygemm_attr_set = false;
  if (!ygemm_attr_set) {
    hipFuncSetAttribute(reinterpret_cast<const void*>(y_gemm),
                        hipFuncAttributeMaxDynamicSharedMemorySize, 131072);
    ygemm_attr_set = true;
  }

  const dim3 blk(256);

  prep_fused<<<14059, blk, 0, stream>>>(
      enz, sub, prod, enz_b, sub_b, prod_b,
      enz_Wq, enz_Wk, sub_Wq, sub_Wk, prod_Wq, prod_Wk,
      eWq_b, eWk_b, sWq_b, sWk_b, pWq_b, pWk_b,
      enz_bq, sub_bq, prod_bq, enz_bv, sub_bv, prod_bv,
      W3t, u_e_s, wsum_es, out);

  fold_w3<<<60, blk, 0, stream>>>(eWq_b, eWk_b, sWq_b, sWk_b, pWq_b, pWk_b, W3t);

  y_gemm<<<256, 512, 131072, stream>>>(enz_b, W3t, Y);

  score_fused<<<512, blk, 0, stream>>>(
      Y, sub_b, prod_b, iw, u_e_s, Sc_se, Sc_pe, l_se, l_pe, wsum_es, wsum_ep);

  colsum2<<<256, blk, 0, stream>>>(Sc_se, Sc_pe, l_se, l_pe, wsum_se, wsum_pe);

  wx_fused<<<384, blk, 0, stream>>>(
      wsum_se, wsum_pe, wsum_es, wsum_ep, enz_b, sub_b, prod_b,
      wx_se, wx_pe, wx_es, wx_ep);

  out_gemv<<<96, blk, 0, stream>>>(
      wx_es, wx_se, wx_ep, wx_pe, enz_Wv, sub_Wv, prod_Wv, out);
}